// Round 3
// baseline (225.149 us; speedup 1.0000x reference)
//
#include <hip/hip_runtime.h>
#include <math.h>

#define DEV_INLINE __device__ __forceinline__

// Branch-free fast atan2. Max error ~1e-5 rad; output sensitivity to alpha is
// ~0.07 (2 iters x DT x MLP slope x chassis gains) -> ~1e-6 abs error
// contribution vs 1.4e-2 threshold.
DEV_INLINE float fast_atan2f(float y, float x) {
    const float kPI  = 3.14159265358979323846f;
    const float kPI2 = 1.57079632679489661923f;
    float ax = fabsf(x), ay = fabsf(y);
    float mx = fmaxf(ax, ay);
    float mn = fminf(ax, ay);
    float a  = mn * __builtin_amdgcn_rcpf(mx);
    float s  = a * a;
    float p  = -0.01172120f;
    p = fmaf(p, s,  0.05265332f);
    p = fmaf(p, s, -0.11643287f);
    p = fmaf(p, s,  0.19354346f);
    p = fmaf(p, s, -0.33262347f);
    p = fmaf(p, s,  0.99997726f);
    float r = a * p;                       // atan(mn/mx) in [0, pi/4]
    r = (ay > ax)   ? (kPI2 - r) : r;      // reflect across pi/4
    r = (x < 0.0f)  ? (kPI  - r) : r;      // reflect across pi/2
    return copysignf(r, y);
}

DEV_INLINE float mlp12(float a, const float* __restrict__ w1,
                       const float* __restrict__ b1,
                       const float* __restrict__ w2, float b2) {
    float acc = b2;
#pragma unroll
    for (int j = 0; j < 12; ++j) {
        float h = fmaxf(fmaf(a, w1[j], b1[j]), 0.0f);
        acc = fmaf(h, w2[j], acc);
    }
    return acc;
}

struct Row { float pwm, theta, vx0, vy0, w0, pitch; };

DEV_INLINE void compute_row(const Row& in,
                            const float* fw1, const float* fb1, const float* fw2, float fb2,
                            const float* rw1, const float* rb1, const float* rw2, float rb2,
                            float rxw, float rxb,
                            float& o0, float& o1, float& o2) {
    const float kLF     = 1.5f;
    const float kLR     = 1.4f;
    const float kCM1    = 550.0f;
    const float kCM2    = 650.0f;
    const float kDT     = 0.01f;
    const float kGRAV   = 9.8f;
    const float kCDRIVE = (float)(3.45 * 0.919 / (0.34 * 1265.0));
    const float kWF     = (float)(1265.0 * 1.5 / 2000.0);  // MASS*LF/IZ
    const float kWR     = (float)(1265.0 * 1.4 / 2000.0);  // MASS*LR/IZ

    const float st = __sinf(in.theta);
    const float ct = __cosf(in.theta);
    const float sp = __sinf(in.pitch);
    const float a_pred = (in.pwm > 0.0f ? kCM1 : kCM2) * in.pwm * kCDRIVE;

    o0 = 0.0f; o1 = 0.0f; o2 = 0.0f;
#pragma unroll
    for (int it = 0; it < 2; ++it) {
        const float vx = in.vx0 + o0;
        const float vy = in.vy0 + o1;
        const float w  = in.w0  + o2;

        const float af = in.theta - fast_atan2f(fmaf(w, kLF, vy), vx);
        const float ar = fast_atan2f(fmaf(w, kLR, -vy), vx);

        const float sf  = af > 0.0f ? 1.0f : -1.0f;
        const float Ffy = sf * mlp12(sf * af, fw1, fb1, fw2, fb2);
        const float sr  = ar > 0.0f ? 1.0f : -1.0f;
        const float Fry = sr * mlp12(sr * ar, rw1, rb1, rw2, rb2);

        const float Frx = fmaf(rxw * vx, vx, a_pred + rxb);

        const float vx_dot = Frx - Ffy * st + vy * w - kGRAV * sp;
        const float vy_dot = Fry + Ffy * ct - vx * w;
        const float w_dot  = kWF * Ffy * ct - kWR * Fry;

        o0 = fmaf(kDT, vx_dot, o0);
        o1 = fmaf(kDT, vy_dot, o1);
        o2 = fmaf(kDT, w_dot,  o2);
    }
}

// 512 rows / block, 256 threads, 2 rows/thread.
// Inputs staged through LDS so every global load is lane-contiguous float4.
__global__ __launch_bounds__(256) void dyn_kernel(
    const float4* __restrict__ x4,
    const float* __restrict__ fy_w1, const float* __restrict__ fy_b1,
    const float* __restrict__ fy_w2, const float* __restrict__ fy_b2,
    const float* __restrict__ ry_w1, const float* __restrict__ ry_b1,
    const float* __restrict__ ry_w2, const float* __restrict__ ry_b2,
    const float* __restrict__ rx_w, const float* __restrict__ rx_b,
    float* __restrict__ out, int nrows) {
    __shared__ float sIn[8 * 512];  // column-major: sIn[c*512 + row], 16 KB

    // ---- uniform weights (uniform addresses -> scalar loads) ----
    float fw1[12], fb1[12], fw2[12];
    float rw1[12], rb1[12], rw2[12];
#pragma unroll
    for (int j = 0; j < 12; ++j) {
        fw1[j] = fy_w1[j]; fb1[j] = fy_b1[j]; fw2[j] = fy_w2[j];
        rw1[j] = ry_w1[j]; rb1[j] = ry_b1[j]; rw2[j] = ry_w2[j];
    }
    const float fb2 = fy_b2[0];
    const float rb2 = ry_b2[0];
    const float rxw = rx_w[0];
    const float rxb = rx_b[0];

    const int tid = threadIdx.x;
    const long long rowBase = (long long)blockIdx.x * 512;
    const long long f4Base  = rowBase * 2;        // float4 index of block start
    const long long f4Max   = (long long)nrows * 2;

    // ---- stage: 4 perfectly-coalesced float4 loads -> LDS transpose ----
#pragma unroll
    for (int q = 0; q < 4; ++q) {
        const int l = q * 256 + tid;              // local float4 index [0,1024)
        const long long g = f4Base + l;
        float4 f = make_float4(0.f, 0.f, 0.f, 0.f);
        if (g < f4Max) f = x4[g];
        const int row = l >> 1;                   // [0,512)
        const int c0  = (l & 1) * 4;
        // bank = row % 32; lanes share row in pairs -> 2-way alias (free)
        sIn[(c0 + 0) * 512 + row] = f.x;
        sIn[(c0 + 1) * 512 + row] = f.y;
        sIn[(c0 + 2) * 512 + row] = f.z;
        sIn[(c0 + 3) * 512 + row] = f.w;
    }
    __syncthreads();

    // ---- compute 2 rows/thread; LDS reads stride-1 (conflict-free) ----
    float o[2][3];
#pragma unroll
    for (int h = 0; h < 2; ++h) {
        const int r = h * 256 + tid;
        Row in;
        in.pwm   = sIn[0 * 512 + r];
        in.theta = sIn[2 * 512 + r];
        in.vx0   = sIn[3 * 512 + r];
        in.vy0   = sIn[4 * 512 + r];
        in.w0    = sIn[5 * 512 + r];
        in.pitch = sIn[7 * 512 + r];
        compute_row(in, fw1, fb1, fw2, fb2, rw1, rb1, rw2, rb2, rxw, rxb,
                    o[h][0], o[h][1], o[h][2]);
    }
    __syncthreads();  // done reading sIn; reuse it as the output buffer

    // ---- output transpose: write stride-3 (2-way alias, free), read stride-1
    float* sOut = sIn;  // needs 512*3 = 1536 floats
#pragma unroll
    for (int h = 0; h < 2; ++h) {
        const int r = h * 256 + tid;
        sOut[r * 3 + 0] = o[h][0];
        sOut[r * 3 + 1] = o[h][1];
        sOut[r * 3 + 2] = o[h][2];
    }
    __syncthreads();

    const long long gbase = rowBase * 3;
    const long long gmax  = (long long)nrows * 3;
#pragma unroll
    for (int j = 0; j < 6; ++j) {
        const long long gi = gbase + j * 256 + tid;
        if (gi < gmax) out[gi] = sOut[j * 256 + tid];
    }
}

extern "C" void kernel_launch(void* const* d_in, const int* in_sizes, int n_in,
                              void* d_out, int out_size, void* d_ws, size_t ws_size,
                              hipStream_t stream) {
    const float4* x4   = (const float4*)d_in[0];
    const float* fy_w1 = (const float*)d_in[1];
    const float* fy_b1 = (const float*)d_in[2];
    const float* fy_w2 = (const float*)d_in[3];
    const float* fy_b2 = (const float*)d_in[4];
    const float* ry_w1 = (const float*)d_in[5];
    const float* ry_b1 = (const float*)d_in[6];
    const float* ry_w2 = (const float*)d_in[7];
    const float* ry_b2 = (const float*)d_in[8];
    const float* rx_w  = (const float*)d_in[9];
    const float* rx_b  = (const float*)d_in[10];

    const int nrows = in_sizes[0] / 8;
    const int rows_per_block = 512;
    const int blocks = (nrows + rows_per_block - 1) / rows_per_block;

    dyn_kernel<<<blocks, 256, 0, stream>>>(
        x4, fy_w1, fy_b1, fy_w2, fy_b2, ry_w1, ry_b1, ry_w2, ry_b2, rx_w, rx_b,
        (float*)d_out, nrows);
}

// Round 4
// 224.495 us; speedup vs baseline: 1.0029x; 1.0029x over previous
//
#include <hip/hip_runtime.h>
#include <math.h>

#define DEV_INLINE __device__ __forceinline__

// Branch-free fast atan2. Max error ~1e-5 rad; output sensitivity to alpha is
// ~0.07 (2 iters x DT x MLP slope x chassis gains) -> ~1e-6 abs error
// contribution vs 1.4e-2 threshold.
DEV_INLINE float fast_atan2f(float y, float x) {
    const float kPI  = 3.14159265358979323846f;
    const float kPI2 = 1.57079632679489661923f;
    float ax = fabsf(x), ay = fabsf(y);
    float mx = fmaxf(ax, ay);
    float mn = fminf(ax, ay);
    float a  = mn * __builtin_amdgcn_rcpf(mx);
    float s  = a * a;
    float p  = -0.01172120f;
    p = fmaf(p, s,  0.05265332f);
    p = fmaf(p, s, -0.11643287f);
    p = fmaf(p, s,  0.19354346f);
    p = fmaf(p, s, -0.33262347f);
    p = fmaf(p, s,  0.99997726f);
    float r = a * p;                       // atan(mn/mx) in [0, pi/4]
    r = (ay > ax)   ? (kPI2 - r) : r;      // reflect across pi/4
    r = (x < 0.0f)  ? (kPI  - r) : r;      // reflect across pi/2
    return copysignf(r, y);
}

DEV_INLINE float mlp12(float a, const float* __restrict__ w1,
                       const float* __restrict__ b1,
                       const float* __restrict__ w2, float b2) {
    float acc = b2;
#pragma unroll
    for (int j = 0; j < 12; ++j) {
        float h = fmaxf(fmaf(a, w1[j], b1[j]), 0.0f);
        acc = fmaf(h, w2[j], acc);
    }
    return acc;
}

DEV_INLINE void compute_row(float pwm, float theta, float vx0, float vy0,
                            float w0, float pitch,
                            const float* fw1, const float* fb1, const float* fw2, float fb2,
                            const float* rw1, const float* rb1, const float* rw2, float rb2,
                            float rxw, float rxb,
                            float& o0, float& o1, float& o2) {
    const float kLF     = 1.5f;
    const float kLR     = 1.4f;
    const float kCM1    = 550.0f;
    const float kCM2    = 650.0f;
    const float kDT     = 0.01f;
    const float kGRAV   = 9.8f;
    const float kCDRIVE = (float)(3.45 * 0.919 / (0.34 * 1265.0));
    const float kWF     = (float)(1265.0 * 1.5 / 2000.0);  // MASS*LF/IZ
    const float kWR     = (float)(1265.0 * 1.4 / 2000.0);  // MASS*LR/IZ

    const float st = __sinf(theta);
    const float ct = __cosf(theta);
    const float sp = __sinf(pitch);
    const float a_pred = (pwm > 0.0f ? kCM1 : kCM2) * pwm * kCDRIVE;

    o0 = 0.0f; o1 = 0.0f; o2 = 0.0f;
#pragma unroll
    for (int it = 0; it < 2; ++it) {
        const float vx = vx0 + o0;
        const float vy = vy0 + o1;
        const float w  = w0  + o2;

        const float af = theta - fast_atan2f(fmaf(w, kLF, vy), vx);
        const float ar = fast_atan2f(fmaf(w, kLR, -vy), vx);

        const float sf  = af > 0.0f ? 1.0f : -1.0f;
        const float Ffy = sf * mlp12(sf * af, fw1, fb1, fw2, fb2);
        const float sr  = ar > 0.0f ? 1.0f : -1.0f;
        const float Fry = sr * mlp12(sr * ar, rw1, rb1, rw2, rb2);

        const float Frx = fmaf(rxw * vx, vx, a_pred + rxb);

        const float vx_dot = Frx - Ffy * st + vy * w - kGRAV * sp;
        const float vy_dot = Fry + Ffy * ct - vx * w;
        const float w_dot  = kWF * Ffy * ct - kWR * Fry;

        o0 = fmaf(kDT, vx_dot, o0);
        o1 = fmaf(kDT, vy_dot, o1);
        o2 = fmaf(kDT, w_dot,  o2);
    }
}

// 512 rows/block, 256 threads, 2 independent rows/thread (ILP + 4KB/wave of
// loads in flight). Direct global loads (no input staging — R3 showed the LDS
// round-trip costs more than it saves); LDS transpose on the output only.
__global__ __launch_bounds__(256) void dyn_kernel(
    const float4* __restrict__ x4,
    const float* __restrict__ fy_w1, const float* __restrict__ fy_b1,
    const float* __restrict__ fy_w2, const float* __restrict__ fy_b2,
    const float* __restrict__ ry_w1, const float* __restrict__ ry_b1,
    const float* __restrict__ ry_w2, const float* __restrict__ ry_b2,
    const float* __restrict__ rx_w, const float* __restrict__ rx_b,
    float* __restrict__ out, int nrows) {
    __shared__ float sOut[1536];  // 512 rows x 3 floats

    // ---- uniform weights (uniform addresses -> scalar loads) ----
    float fw1[12], fb1[12], fw2[12];
    float rw1[12], rb1[12], rw2[12];
#pragma unroll
    for (int j = 0; j < 12; ++j) {
        fw1[j] = fy_w1[j]; fb1[j] = fy_b1[j]; fw2[j] = fy_w2[j];
        rw1[j] = ry_w1[j]; rb1[j] = ry_b1[j]; rw2[j] = ry_w2[j];
    }
    const float fb2 = fy_b2[0];
    const float rb2 = ry_b2[0];
    const float rxw = rx_w[0];
    const float rxb = rx_b[0];

    const int tid = threadIdx.x;
    const long long rowBase = (long long)blockIdx.x * 512;
    const long long r0 = rowBase + tid;
    const long long r1 = rowBase + 256 + tid;

    // ---- issue all 4 loads up front (2 KB/lane-pair in flight) ----
    float4 lo0 = make_float4(0.f, 0.f, 1.f, 0.f), hi0 = lo0;
    float4 lo1 = lo0, hi1 = lo0;
    if (r0 < nrows) { lo0 = x4[2 * r0]; hi0 = x4[2 * r0 + 1]; }
    if (r1 < nrows) { lo1 = x4[2 * r1]; hi1 = x4[2 * r1 + 1]; }

    // ---- two independent dependency chains ----
    float a0, a1, a2, b0, b1v, b2v;
    compute_row(lo0.x, lo0.z, lo0.w, hi0.x, hi0.y, hi0.w,
                fw1, fb1, fw2, fb2, rw1, rb1, rw2, rb2, rxw, rxb, a0, a1, a2);
    compute_row(lo1.x, lo1.z, lo1.w, hi1.x, hi1.y, hi1.w,
                fw1, fb1, fw2, fb2, rw1, rb1, rw2, rb2, rxw, rxb, b0, b1v, b2v);

    // ---- output transpose: write stride-3 (2-way alias, free), read stride-1
    sOut[tid * 3 + 0] = a0;
    sOut[tid * 3 + 1] = a1;
    sOut[tid * 3 + 2] = a2;
    sOut[(256 + tid) * 3 + 0] = b0;
    sOut[(256 + tid) * 3 + 1] = b1v;
    sOut[(256 + tid) * 3 + 2] = b2v;
    __syncthreads();

    const long long gbase = rowBase * 3;
    const long long gmax  = (long long)nrows * 3;
#pragma unroll
    for (int j = 0; j < 6; ++j) {
        const long long gi = gbase + j * 256 + tid;
        if (gi < gmax) __builtin_nontemporal_store(sOut[j * 256 + tid], &out[gi]);
    }
}

extern "C" void kernel_launch(void* const* d_in, const int* in_sizes, int n_in,
                              void* d_out, int out_size, void* d_ws, size_t ws_size,
                              hipStream_t stream) {
    const float4* x4   = (const float4*)d_in[0];
    const float* fy_w1 = (const float*)d_in[1];
    const float* fy_b1 = (const float*)d_in[2];
    const float* fy_w2 = (const float*)d_in[3];
    const float* fy_b2 = (const float*)d_in[4];
    const float* ry_w1 = (const float*)d_in[5];
    const float* ry_b1 = (const float*)d_in[6];
    const float* ry_w2 = (const float*)d_in[7];
    const float* ry_b2 = (const float*)d_in[8];
    const float* rx_w  = (const float*)d_in[9];
    const float* rx_b  = (const float*)d_in[10];

    const int nrows = in_sizes[0] / 8;
    const int rows_per_block = 512;
    const int blocks = (nrows + rows_per_block - 1) / rows_per_block;

    dyn_kernel<<<blocks, 256, 0, stream>>>(
        x4, fy_w1, fy_b1, fy_w2, fy_b2, ry_w1, ry_b1, ry_w2, ry_b2, rx_w, rx_b,
        (float*)d_out, nrows);
}